// Round 5
// baseline (585.622 us; speedup 1.0000x reference)
//
#include <hip/hip_runtime.h>
#include <hip/hip_bf16.h>
#include <math.h>

// L=1024, BT=64, D=768, HID=192, NH=4, hd=48, K=5, Hh=Ww=32, T=16, M=65536
//
// bf16 pipeline:
//  cvt: x -> x_bf, weights -> bf16
//  1. xs0   = x_bf @ fc1_w.T + b          (M x 192) bf16, rows m = l*64+b
//  2. a     = xs0 @ convA_w.T + b         (M x 64)  bf16
//  3. bconv = a @ convB_w.T + b           (M x 192) bf16
//  4. fuse: g = gelu(bconv+xs0); xs_sp[spatial]=g; ln_sp=LN(g)   bf16
//  5. qkv   = ln_sp @ qkv_w.T + b         (M x 576) bf16 spatial
//  6. natten -> o                         (M x 192) bf16 (LDS stencil tile)
//  7. y     = o @ proj_w.T + b + xs_sp    (M x 192) bf16 spatial
//  8. out   = scatter(y @ fc2_w.T + b + x)  fp32 permuted, SWAPPED mfma.

typedef __attribute__((ext_vector_type(4))) float f32x4;
typedef __attribute__((ext_vector_type(8))) __bf16 bf16x8;
typedef const __attribute__((address_space(1))) void gv_t;
typedef __attribute__((address_space(3))) void lv_t;

#define GBM 128
#define GBN 64
#define GBK 64

// ---------------- MFMA GEMM: C = A @ W^T + bias (+epilogue) ----------------
template <int MODE>
__global__ __launch_bounds__(256) void mfma_gemm_kernel(
    const __hip_bfloat16* __restrict__ A, const __hip_bfloat16* __restrict__ W,
    const float* __restrict__ bias, const __hip_bfloat16* __restrict__ res,
    const float* __restrict__ xin, void* __restrict__ Cout,
    int M, int N, int K) {
  __shared__ __hip_bfloat16 Asm[2][GBM * GBK];
  __shared__ __hip_bfloat16 Bsm[2][GBN * GBK];

  const int tid = threadIdx.x;
  const int lane = tid & 63;
  const int wave = tid >> 6;

  // chunked XCD swizzle (all grids have nwg % 8 == 0)
  const int gx = gridDim.x;
  const int nwg = gx * gridDim.y;
  int id = blockIdx.y * gx + blockIdx.x;
  id = (id & 7) * (nwg >> 3) + (id >> 3);
  const int bm0 = (id / gx) * GBM;
  const int bn0 = (id % gx) * GBN;

  const int wm0 = (wave >> 1) * 64;
  const int wn0 = (wave & 1) * 32;

  const int l15 = lane & 15;
  const int l7 = lane & 7;
  const int lg = lane >> 4;

  f32x4 acc[4][2] = {};

  int aro[4], bro[2], ksw[2];
#pragma unroll
  for (int mi = 0; mi < 4; ++mi) aro[mi] = (wm0 + mi * 16 + l15) * (GBK * 2);
#pragma unroll
  for (int nj = 0; nj < 2; ++nj) bro[nj] = (wn0 + nj * 16 + l15) * (GBK * 2);
#pragma unroll
  for (int kk = 0; kk < 2; ++kk) ksw[kk] = ((lg * 16 + kk * 64) ^ (l7 << 4));

  const int nk = K / GBK;

  auto stage = [&](int buf, int k0) {
#pragma unroll
    for (int q = 0; q < 4; ++q) {
      int ci = tid + q * 256;            // A chunks (16B each)
      int r = ci >> 3;
      int sc = (ci & 7) ^ (r & 7);
      const __hip_bfloat16* src = A + (size_t)(bm0 + r) * K + (k0 + sc * 8);
      __builtin_amdgcn_global_load_lds((gv_t*)src, (lv_t*)&Asm[buf][ci * 8], 16, 0, 0);
    }
#pragma unroll
    for (int q = 0; q < 2; ++q) {
      int ci = tid + q * 256;            // B chunks
      int r = ci >> 3;
      int sc = (ci & 7) ^ (r & 7);
      const __hip_bfloat16* src = W + (size_t)(bn0 + r) * K + (k0 + sc * 8);
      __builtin_amdgcn_global_load_lds((gv_t*)src, (lv_t*)&Bsm[buf][ci * 8], 16, 0, 0);
    }
  };

  stage(0, 0);
  for (int kt = 0; kt < nk; ++kt) {
    const int cur = kt & 1;
    __syncthreads();
    if (kt + 1 < nk) stage(cur ^ 1, (kt + 1) * GBK);
    const char* Ab = (const char*)&Asm[cur][0];
    const char* Bb = (const char*)&Bsm[cur][0];
#pragma unroll
    for (int kk = 0; kk < 2; ++kk) {
      bf16x8 af[4], bfr[2];
#pragma unroll
      for (int mi = 0; mi < 4; ++mi)
        af[mi] = *(const bf16x8*)(Ab + aro[mi] + ksw[kk]);
#pragma unroll
      for (int nj = 0; nj < 2; ++nj)
        bfr[nj] = *(const bf16x8*)(Bb + bro[nj] + ksw[kk]);
#pragma unroll
      for (int mi = 0; mi < 4; ++mi)
#pragma unroll
        for (int nj = 0; nj < 2; ++nj) {
          if constexpr (MODE == 2)
            acc[mi][nj] = __builtin_amdgcn_mfma_f32_16x16x32_bf16(
                bfr[nj], af[mi], acc[mi][nj], 0, 0, 0);   // D[row=n][col=m]
          else
            acc[mi][nj] = __builtin_amdgcn_mfma_f32_16x16x32_bf16(
                af[mi], bfr[nj], acc[mi][nj], 0, 0, 0);   // D[row=m][col=n]
        }
    }
  }

  if constexpr (MODE == 2) {
    float* Cf = (float*)Cout;
#pragma unroll
    for (int nj = 0; nj < 2; ++nj) {
      const int n0 = bn0 + wn0 + nj * 16 + lg * 4;
      const f32x4 bi4 = *(const f32x4*)(bias + n0);
#pragma unroll
      for (int mi = 0; mi < 4; ++mi) {
        const int m = bm0 + wm0 + mi * 16 + l15;   // col = lane&15 -> m
        const int b = m >> 10;
        const int ll = m & 1023;
        const f32x4 xv = *(const f32x4*)(xin + (size_t)((ll << 6) | b) * 768 + n0);
        const size_t ob = (((size_t)(b >> 4) * 768 + n0) * 16 + (b & 15)) * 1024 + ll;
#pragma unroll
        for (int r = 0; r < 4; ++r) {
          Cf[ob + (size_t)r * 16384] = acc[mi][nj][r] + bi4[r] + xv[r];
        }
      }
    }
  } else {
    __hip_bfloat16* Cb = (__hip_bfloat16*)Cout;
#pragma unroll
    for (int nj = 0; nj < 2; ++nj) {
      const int n = bn0 + wn0 + nj * 16 + l15;
      const float bi = bias[n];
#pragma unroll
      for (int mi = 0; mi < 4; ++mi) {
        const int mb = bm0 + wm0 + mi * 16 + lg * 4;
        f32x4 v = acc[mi][nj];
#pragma unroll
        for (int r = 0; r < 4; ++r) {
          const int m = mb + r;
          float val = v[r] + bi;
          if constexpr (MODE == 1) val += __bfloat162float(res[(size_t)m * N + n]);
          Cb[(size_t)m * N + n] = __float2bfloat16(val);
        }
      }
    }
  }
}

// ---------------- fp32 -> bf16 convert (vectorized) ----------------
__global__ __launch_bounds__(256) void cvt_kernel(
    const float* __restrict__ in, __hip_bfloat16* __restrict__ out, int n4) {
  int i = blockIdx.x * 256 + threadIdx.x;
  if (i >= n4) return;
  float4 v = ((const float4*)in)[i];
  union { unsigned short u[4]; uint2 d; } o;
  __hip_bfloat16 b0 = __float2bfloat16(v.x);
  __hip_bfloat16 b1 = __float2bfloat16(v.y);
  __hip_bfloat16 b2 = __float2bfloat16(v.z);
  __hip_bfloat16 b3 = __float2bfloat16(v.w);
  o.u[0] = *(unsigned short*)&b0; o.u[1] = *(unsigned short*)&b1;
  o.u[2] = *(unsigned short*)&b2; o.u[3] = *(unsigned short*)&b3;
  ((uint2*)out)[i] = o.d;
}

// ---------------- GeLU + residual + transpose + LayerNorm ----------------
__global__ __launch_bounds__(256) void fuse_gelu_ln_kernel(
    const __hip_bfloat16* __restrict__ bconv, const __hip_bfloat16* __restrict__ xs0,
    const float* __restrict__ ln_g, const float* __restrict__ ln_b,
    __hip_bfloat16* __restrict__ xs_sp, __hip_bfloat16* __restrict__ ln_sp) {
  const int r = blockIdx.x * 4 + (threadIdx.x >> 6);  // m = l*64 + b
  const int tid = threadIdx.x & 63;
  const int l = r >> 6;
  const int b = r & 63;
  const size_t src = (size_t)r * 192;
  const size_t dst = (size_t)((b << 10) | l) * 192;

  float g[3];
  float s1 = 0.0f, s2 = 0.0f;
#pragma unroll
  for (int q = 0; q < 3; ++q) {
    int c = tid + q * 64;
    float v = __bfloat162float(bconv[src + c]) + __bfloat162float(xs0[src + c]);
    float ge = 0.5f * v * (1.0f + erff(v * 0.70710678118654752f));
    g[q] = ge;
    s1 += ge;
    s2 += ge * ge;
  }
#pragma unroll
  for (int off = 32; off; off >>= 1) {
    s1 += __shfl_xor(s1, off);
    s2 += __shfl_xor(s2, off);
  }
  float mean = s1 * (1.0f / 192.0f);
  float var = s2 * (1.0f / 192.0f) - mean * mean;
  float rstd = rsqrtf(var + 1e-5f);
#pragma unroll
  for (int q = 0; q < 3; ++q) {
    int c = tid + q * 64;
    xs_sp[dst + c] = __float2bfloat16(g[q]);
    ln_sp[dst + c] = __float2bfloat16((g[q] - mean) * rstd * ln_g[c] + ln_b[c]);
  }
}

// ---------------- Neighborhood attention: LDS stencil tile ----------------
// Block = 8x8 pixel tile. 4 waves = 4 heads, 1 pixel/lane.
// Phase 1: stage 12x12 K-halo (all heads, 55.3KB) -> scores from LDS.
// Phase 2: restage same LDS with V-halo -> PV from LDS (t-outer, pv[8] live).
// sched_barrier(VALU|SALU may cross) bounds in-flight ds_read batching so the
// long-lived arrays (qv/s) stay in registers (R4 spilled at 256 VGPR).
__global__ __launch_bounds__(256, 4) void natten_kernel(
    const __hip_bfloat16* __restrict__ qkv, const float* __restrict__ rpb,
    __hip_bfloat16* __restrict__ o) {
  __shared__ __hip_bfloat16 sm[3456 * 8];   // 144 px * 24 chunks * 16B = 55296 B

  const int tid = threadIdx.x;
  const int wid = tid >> 6;        // head
  const int lane = tid & 63;
  const int tile = blockIdx.x;     // 1024 tiles
  const int b = tile >> 4;
  const int ti = (tile >> 2) & 3;
  const int tj = tile & 3;
  const int hs = min(max(ti * 8 - 2, 0), 20);
  const int ws = min(max(tj * 8 - 2, 0), 20);
  const int i = ti * 8 + (lane >> 3);
  const int j = tj * 8 + (lane & 7);
  const int pix = (b << 10) + (i << 5) + j;
  const int ih0 = min(max(i - 2, 0), 27);
  const int iw0 = min(max(j - 2, 0), 27);
  const int oi = ih0 - hs;         // 0..7 (halo-local)
  const int oj = iw0 - ws;
  const int dbh = ih0 - i + 4;
  const int dbw = iw0 - j + 4;

  auto stageKV = [&](int seg) {    // seg: 192 (K) or 384 (V), element offset
#pragma unroll
    for (int it = 0; it < 14; ++it) {
      int ci = tid + it * 256;     // 0..3455 chunks
      if (it < 13 || ci < 3456) {
        int r = ci / 24;           // halo pixel 0..143
        int c = ci % 24;           // chunk within row
        int hr = r / 12, wr = r % 12;
        int sc = c ^ (r & 7);      // inverse-swizzled source chunk
        const __hip_bfloat16* src =
            qkv + (size_t)((b << 10) + (hs + hr) * 32 + (ws + wr)) * 576 + seg + sc * 8;
        __builtin_amdgcn_global_load_lds((gv_t*)src, (lv_t*)&sm[ci * 8], 16, 0, 0);
      }
    }
  };

  stageKV(192);                    // K halo in flight

  // load + scale own Q row while K stages
  float qv[48];
  {
    const bf16x8* qp = (const bf16x8*)(qkv + (size_t)pix * 576 + wid * 48);
#pragma unroll
    for (int t = 0; t < 6; ++t) {
      bf16x8 v = qp[t];
#pragma unroll
      for (int u = 0; u < 8; ++u)
        qv[t * 8 + u] = (float)v[u] * 0.14433756729740643f;
    }
  }
  __syncthreads();                 // K staged

  const char* smb = (const char*)sm;
  const int wb = wid * 6;
  float s[25];
#pragma unroll
  for (int x = 0; x < 5; ++x) {
#pragma unroll
    for (int y = 0; y < 5; ++y) {
      const int r = (oi + x) * 12 + (oj + y);
      const int rb = r * 384;
      const int sw = r & 7;
      float a = 0.0f;
#pragma unroll
      for (int t = 0; t < 6; ++t) {
        bf16x8 kv = *(const bf16x8*)(smb + rb + (((wb + t) ^ sw) << 4));
#pragma unroll
        for (int u = 0; u < 8; ++u) a += qv[t * 8 + u] * (float)kv[u];
      }
      s[x * 5 + y] = a + rpb[wid * 81 + (dbh + x) * 9 + (dbw + y)];
      __builtin_amdgcn_sched_barrier(0x6);   // only VALU/SALU may cross
    }
  }
  __syncthreads();                 // all waves done reading K
  stageKV(384);                    // V halo in flight

  // softmax (overlaps V staging)
  float mx = s[0];
#pragma unroll
  for (int n = 1; n < 25; ++n) mx = fmaxf(mx, s[n]);
  float sum = 0.0f;
#pragma unroll
  for (int n = 0; n < 25; ++n) {
    s[n] = __expf(s[n] - mx);
    sum += s[n];
  }
  const float inv = 1.0f / sum;
  __syncthreads();                 // V staged

  bf16x8* op = (bf16x8*)(o + (size_t)pix * 192 + wid * 48);
#pragma unroll
  for (int t = 0; t < 6; ++t) {
    float pv[8] = {};
#pragma unroll
    for (int x = 0; x < 5; ++x) {
#pragma unroll
      for (int y = 0; y < 5; ++y) {
        const int r = (oi + x) * 12 + (oj + y);
        const bf16x8 vv =
            *(const bf16x8*)(smb + r * 384 + (((wb + t) ^ (r & 7)) << 4));
        const float w = s[x * 5 + y];
#pragma unroll
        for (int u = 0; u < 8; ++u) pv[u] += w * (float)vv[u];
      }
      __builtin_amdgcn_sched_barrier(0x6);   // only VALU/SALU may cross
    }
    bf16x8 ov;
#pragma unroll
    for (int u = 0; u < 8; ++u) ov[u] = (__bf16)(pv[u] * inv);
    op[t] = ov;
  }
}

extern "C" void kernel_launch(void* const* d_in, const int* in_sizes, int n_in,
                              void* d_out, int out_size, void* d_ws, size_t ws_size,
                              hipStream_t stream) {
  const float* x       = (const float*)d_in[0];
  const float* fc1_w   = (const float*)d_in[1];
  const float* fc1_b   = (const float*)d_in[2];
  const float* convA_w = (const float*)d_in[3];
  const float* convA_b = (const float*)d_in[4];
  const float* convB_w = (const float*)d_in[5];
  const float* convB_b = (const float*)d_in[6];
  const float* ln_g    = (const float*)d_in[7];
  const float* ln_b    = (const float*)d_in[8];
  const float* qkv_w   = (const float*)d_in[9];
  const float* qkv_b   = (const float*)d_in[10];
  const float* rpb     = (const float*)d_in[11];
  const float* proj_w  = (const float*)d_in[12];
  const float* proj_b  = (const float*)d_in[13];
  const float* fc2_w   = (const float*)d_in[14];
  const float* fc2_b   = (const float*)d_in[15];
  float* out = (float*)d_out;

  const int M = 65536;
  char* W0 = (char*)d_ws;
  __hip_bfloat16* x_bf  = (__hip_bfloat16*)W0;                 // 50,331,648 elems
  __hip_bfloat16* wfc1  = (__hip_bfloat16*)(W0 + 100663296);
  __hip_bfloat16* wcvA  = wfc1 + 147456;
  __hip_bfloat16* wcvB  = wcvA + 12288;
  __hip_bfloat16* wqkv  = wcvB + 12288;
  __hip_bfloat16* wproj = wqkv + 110592;
  __hip_bfloat16* wfc2  = wproj + 36864;
  __hip_bfloat16* reg1  = wfc2 + 147456;                       // 37,748,736 elems
  __hip_bfloat16* xs0   = reg1;
  __hip_bfloat16* bconv = reg1 + 12582912;
  __hip_bfloat16* abuf  = reg1 + 25165824;
  __hip_bfloat16* qkvb  = reg1;
  __hip_bfloat16* ybuf  = reg1;
  __hip_bfloat16* xs_sp = reg1 + 37748736;                     // 12,582,912
  __hip_bfloat16* ln_sp = xs_sp + 12582912;                    // 12,582,912
  __hip_bfloat16* obuf  = ln_sp;                               // reuse after qkv GEMM

  auto cvt = [&](const float* in, __hip_bfloat16* outp, int n) {
    int n4 = n / 4;
    cvt_kernel<<<(n4 + 255) / 256, 256, 0, stream>>>(in, outp, n4);
  };
  cvt(x, x_bf, 50331648);
  cvt(fc1_w, wfc1, 147456);
  cvt(convA_w, wcvA, 12288);
  cvt(convB_w, wcvB, 12288);
  cvt(qkv_w, wqkv, 110592);
  cvt(proj_w, wproj, 36864);
  cvt(fc2_w, wfc2, 147456);

  // 1. fc1
  mfma_gemm_kernel<0><<<dim3(3, 512), 256, 0, stream>>>(
      x_bf, wfc1, fc1_b, nullptr, nullptr, xs0, M, 192, 768);
  // 2. convA
  mfma_gemm_kernel<0><<<dim3(1, 512), 256, 0, stream>>>(
      xs0, wcvA, convA_b, nullptr, nullptr, abuf, M, 64, 192);
  // 3. convB
  mfma_gemm_kernel<0><<<dim3(3, 512), 256, 0, stream>>>(
      abuf, wcvB, convB_b, nullptr, nullptr, bconv, M, 192, 64);
  // 4. gelu + residual + transpose + LN
  fuse_gelu_ln_kernel<<<16384, 256, 0, stream>>>(bconv, xs0, ln_g, ln_b, xs_sp, ln_sp);
  // 5. qkv
  mfma_gemm_kernel<0><<<dim3(9, 512), 256, 0, stream>>>(
      ln_sp, wqkv, qkv_b, nullptr, nullptr, qkvb, M, 576, 192);
  // 6. natten (LDS stencil, 1024 tiles)
  natten_kernel<<<1024, 256, 0, stream>>>(qkvb, rpb, obuf);
  // 7. proj + residual(xs_sp)
  mfma_gemm_kernel<1><<<dim3(3, 512), 256, 0, stream>>>(
      obuf, wproj, proj_b, xs_sp, nullptr, ybuf, M, 192, 192);
  // 8. fc2 + residual(x) + permuted scatter (swapped-operand, coalesced)
  mfma_gemm_kernel<2><<<dim3(12, 512), 256, 0, stream>>>(
      ybuf, wfc2, fc2_b, nullptr, x, (void*)out, M, 768, 192);
}

// Round 6
// 453.383 us; speedup vs baseline: 1.2917x; 1.2917x over previous
//
#include <hip/hip_runtime.h>
#include <hip/hip_bf16.h>
#include <math.h>

// L=1024, BT=64, D=768, HID=192, NH=4, hd=48, K=5, Hh=Ww=32, T=16, M=65536
//
// bf16 pipeline:
//  cvt: x -> x_bf, weights -> bf16
//  1. xs0   = x_bf @ fc1_w.T + b          (M x 192) bf16, rows m = l*64+b
//  2. a     = xs0 @ convA_w.T + b         (M x 64)  bf16
//  3. bconv = a @ convB_w.T + b           (M x 192) bf16
//  4. fuse: g = gelu(bconv+xs0); xs_sp[spatial]=g; ln_sp=LN(g)   bf16
//  5. qkv   = ln_sp @ qkv_w.T + b         (M x 576) bf16 spatial
//  6. natten -> o                         (M x 192) bf16 (per-head LDS halo)
//  7. y     = o @ proj_w.T + b + xs_sp    (M x 192) bf16 spatial
//  8. out   = scatter(y @ fc2_w.T + b + x)  fp32 permuted, SWAPPED mfma.

typedef __attribute__((ext_vector_type(4))) float f32x4;
typedef __attribute__((ext_vector_type(8))) __bf16 bf16x8;
typedef const __attribute__((address_space(1))) void gv_t;
typedef __attribute__((address_space(3))) void lv_t;

#define GBM 128
#define GBN 64
#define GBK 64

// ---------------- MFMA GEMM: C = A @ W^T + bias (+epilogue) ----------------
template <int MODE>
__global__ __launch_bounds__(256) void mfma_gemm_kernel(
    const __hip_bfloat16* __restrict__ A, const __hip_bfloat16* __restrict__ W,
    const float* __restrict__ bias, const __hip_bfloat16* __restrict__ res,
    const float* __restrict__ xin, void* __restrict__ Cout,
    int M, int N, int K) {
  __shared__ __hip_bfloat16 Asm[2][GBM * GBK];
  __shared__ __hip_bfloat16 Bsm[2][GBN * GBK];

  const int tid = threadIdx.x;
  const int lane = tid & 63;
  const int wave = tid >> 6;

  // chunked XCD swizzle (all grids have nwg % 8 == 0)
  const int gx = gridDim.x;
  const int nwg = gx * gridDim.y;
  int id = blockIdx.y * gx + blockIdx.x;
  id = (id & 7) * (nwg >> 3) + (id >> 3);
  const int bm0 = (id / gx) * GBM;
  const int bn0 = (id % gx) * GBN;

  const int wm0 = (wave >> 1) * 64;
  const int wn0 = (wave & 1) * 32;

  const int l15 = lane & 15;
  const int l7 = lane & 7;
  const int lg = lane >> 4;

  f32x4 acc[4][2] = {};

  int aro[4], bro[2], ksw[2];
#pragma unroll
  for (int mi = 0; mi < 4; ++mi) aro[mi] = (wm0 + mi * 16 + l15) * (GBK * 2);
#pragma unroll
  for (int nj = 0; nj < 2; ++nj) bro[nj] = (wn0 + nj * 16 + l15) * (GBK * 2);
#pragma unroll
  for (int kk = 0; kk < 2; ++kk) ksw[kk] = ((lg * 16 + kk * 64) ^ (l7 << 4));

  const int nk = K / GBK;

  auto stage = [&](int buf, int k0) {
#pragma unroll
    for (int q = 0; q < 4; ++q) {
      int ci = tid + q * 256;            // A chunks (16B each)
      int r = ci >> 3;
      int sc = (ci & 7) ^ (r & 7);
      const __hip_bfloat16* src = A + (size_t)(bm0 + r) * K + (k0 + sc * 8);
      __builtin_amdgcn_global_load_lds((gv_t*)src, (lv_t*)&Asm[buf][ci * 8], 16, 0, 0);
    }
#pragma unroll
    for (int q = 0; q < 2; ++q) {
      int ci = tid + q * 256;            // B chunks
      int r = ci >> 3;
      int sc = (ci & 7) ^ (r & 7);
      const __hip_bfloat16* src = W + (size_t)(bn0 + r) * K + (k0 + sc * 8);
      __builtin_amdgcn_global_load_lds((gv_t*)src, (lv_t*)&Bsm[buf][ci * 8], 16, 0, 0);
    }
  };

  stage(0, 0);
  for (int kt = 0; kt < nk; ++kt) {
    const int cur = kt & 1;
    __syncthreads();
    if (kt + 1 < nk) stage(cur ^ 1, (kt + 1) * GBK);
    const char* Ab = (const char*)&Asm[cur][0];
    const char* Bb = (const char*)&Bsm[cur][0];
#pragma unroll
    for (int kk = 0; kk < 2; ++kk) {
      bf16x8 af[4], bfr[2];
#pragma unroll
      for (int mi = 0; mi < 4; ++mi)
        af[mi] = *(const bf16x8*)(Ab + aro[mi] + ksw[kk]);
#pragma unroll
      for (int nj = 0; nj < 2; ++nj)
        bfr[nj] = *(const bf16x8*)(Bb + bro[nj] + ksw[kk]);
#pragma unroll
      for (int mi = 0; mi < 4; ++mi)
#pragma unroll
        for (int nj = 0; nj < 2; ++nj) {
          if constexpr (MODE == 2)
            acc[mi][nj] = __builtin_amdgcn_mfma_f32_16x16x32_bf16(
                bfr[nj], af[mi], acc[mi][nj], 0, 0, 0);   // D[row=n][col=m]
          else
            acc[mi][nj] = __builtin_amdgcn_mfma_f32_16x16x32_bf16(
                af[mi], bfr[nj], acc[mi][nj], 0, 0, 0);   // D[row=m][col=n]
        }
    }
  }

  if constexpr (MODE == 2) {
    float* Cf = (float*)Cout;
#pragma unroll
    for (int nj = 0; nj < 2; ++nj) {
      const int n0 = bn0 + wn0 + nj * 16 + lg * 4;
      const f32x4 bi4 = *(const f32x4*)(bias + n0);
#pragma unroll
      for (int mi = 0; mi < 4; ++mi) {
        const int m = bm0 + wm0 + mi * 16 + l15;   // col = lane&15 -> m
        const int b = m >> 10;
        const int ll = m & 1023;
        const f32x4 xv = *(const f32x4*)(xin + (size_t)((ll << 6) | b) * 768 + n0);
        const size_t ob = (((size_t)(b >> 4) * 768 + n0) * 16 + (b & 15)) * 1024 + ll;
#pragma unroll
        for (int r = 0; r < 4; ++r) {
          Cf[ob + (size_t)r * 16384] = acc[mi][nj][r] + bi4[r] + xv[r];
        }
      }
    }
  } else {
    __hip_bfloat16* Cb = (__hip_bfloat16*)Cout;
#pragma unroll
    for (int nj = 0; nj < 2; ++nj) {
      const int n = bn0 + wn0 + nj * 16 + l15;
      const float bi = bias[n];
#pragma unroll
      for (int mi = 0; mi < 4; ++mi) {
        const int mb = bm0 + wm0 + mi * 16 + lg * 4;
        f32x4 v = acc[mi][nj];
#pragma unroll
        for (int r = 0; r < 4; ++r) {
          const int m = mb + r;
          float val = v[r] + bi;
          if constexpr (MODE == 1) val += __bfloat162float(res[(size_t)m * N + n]);
          Cb[(size_t)m * N + n] = __float2bfloat16(val);
        }
      }
    }
  }
}

// ---------------- fp32 -> bf16 convert (vectorized) ----------------
__global__ __launch_bounds__(256) void cvt_kernel(
    const float* __restrict__ in, __hip_bfloat16* __restrict__ out, int n4) {
  int i = blockIdx.x * 256 + threadIdx.x;
  if (i >= n4) return;
  float4 v = ((const float4*)in)[i];
  union { unsigned short u[4]; uint2 d; } o;
  __hip_bfloat16 b0 = __float2bfloat16(v.x);
  __hip_bfloat16 b1 = __float2bfloat16(v.y);
  __hip_bfloat16 b2 = __float2bfloat16(v.z);
  __hip_bfloat16 b3 = __float2bfloat16(v.w);
  o.u[0] = *(unsigned short*)&b0; o.u[1] = *(unsigned short*)&b1;
  o.u[2] = *(unsigned short*)&b2; o.u[3] = *(unsigned short*)&b3;
  ((uint2*)out)[i] = o.d;
}

// ---------------- GeLU + residual + transpose + LayerNorm ----------------
__global__ __launch_bounds__(256) void fuse_gelu_ln_kernel(
    const __hip_bfloat16* __restrict__ bconv, const __hip_bfloat16* __restrict__ xs0,
    const float* __restrict__ ln_g, const float* __restrict__ ln_b,
    __hip_bfloat16* __restrict__ xs_sp, __hip_bfloat16* __restrict__ ln_sp) {
  const int r = blockIdx.x * 4 + (threadIdx.x >> 6);  // m = l*64 + b
  const int tid = threadIdx.x & 63;
  const int l = r >> 6;
  const int b = r & 63;
  const size_t src = (size_t)r * 192;
  const size_t dst = (size_t)((b << 10) | l) * 192;

  float g[3];
  float s1 = 0.0f, s2 = 0.0f;
#pragma unroll
  for (int q = 0; q < 3; ++q) {
    int c = tid + q * 64;
    float v = __bfloat162float(bconv[src + c]) + __bfloat162float(xs0[src + c]);
    float ge = 0.5f * v * (1.0f + erff(v * 0.70710678118654752f));
    g[q] = ge;
    s1 += ge;
    s2 += ge * ge;
  }
#pragma unroll
  for (int off = 32; off; off >>= 1) {
    s1 += __shfl_xor(s1, off);
    s2 += __shfl_xor(s2, off);
  }
  float mean = s1 * (1.0f / 192.0f);
  float var = s2 * (1.0f / 192.0f) - mean * mean;
  float rstd = rsqrtf(var + 1e-5f);
#pragma unroll
  for (int q = 0; q < 3; ++q) {
    int c = tid + q * 64;
    xs_sp[dst + c] = __float2bfloat16(g[q]);
    ln_sp[dst + c] = __float2bfloat16((g[q] - mean) * rstd * ln_g[c] + ln_b[c]);
  }
}

// ---------------- Neighborhood attention: per-(tile,head) LDS halo ----------
// Block = one (16x16 pixel tile, head). 256 threads, 1 pixel/lane.
// LDS: 20x20 halo x 48 dims, rows padded to 7 chunks (44.8KB) -> granule
// (7r+t)%8 is coprime-spread => conflict-free b128 reads, linear gload_lds dest.
// Phase1: stage K-halo; QK (s preseeded with rpb). Phase2: restage V in place;
// softmax overlaps V flight; PV t-outer (pv[8] live).
__global__ __launch_bounds__(256) void natten_kernel(
    const __hip_bfloat16* __restrict__ qkv, const float* __restrict__ rpb,
    __hip_bfloat16* __restrict__ o) {
  __shared__ __hip_bfloat16 sm[2800 * 8];   // 400 rows * 7 chunks * 16B = 44800 B

  const int tid = threadIdx.x;
  const int bid = blockIdx.x;      // 1024 = 64 img * 2*2 tiles * 4 heads
  const int head = bid & 3;
  const int tj = (bid >> 2) & 1;
  const int ti = (bid >> 3) & 1;
  const int b = bid >> 4;

  const int hs = ti * 12;          // halo start row (20 rows cover 16+2+2 clamped)
  const int ws = tj * 12;
  const int i = ti * 16 + (tid >> 4);
  const int j = tj * 16 + (tid & 15);
  const int pix = (b << 10) + (i << 5) + j;
  const int ih0 = min(max(i - 2, 0), 27);
  const int iw0 = min(max(j - 2, 0), 27);
  const int oi = ih0 - hs;         // 0..15 (halo-local)
  const int oj = iw0 - ws;
  const int dbh = ih0 - i + 4;
  const int dbw = iw0 - j + 4;
  const size_t qbase = (size_t)(b << 10) * 576 + 192 + head * 48;  // K seg base

  // ---- stage K halo ----
#pragma unroll
  for (int it = 0; it < 11; ++it) {
    int ci = tid + it * 256;       // padded slots 0..2815
    int r = ci / 7;
    int c = ci % 7;
    if (ci < 2800 && c < 6) {
      int hr = r / 20, wr = r % 20;
      const __hip_bfloat16* src =
          qkv + qbase + (size_t)((hs + hr) * 32 + (ws + wr)) * 576 + c * 8;
      __builtin_amdgcn_global_load_lds((gv_t*)src, (lv_t*)&sm[ci * 8], 16, 0, 0);
    }
  }

  // own Q (global load overlaps K staging)
  float qv[48];
  {
    const bf16x8* qp = (const bf16x8*)(qkv + (size_t)pix * 576 + head * 48);
#pragma unroll
    for (int t = 0; t < 6; ++t) {
      bf16x8 v = qp[t];
#pragma unroll
      for (int u = 0; u < 8; ++u)
        qv[t * 8 + u] = (float)v[u] * 0.14433756729740643f;
    }
  }
  // pre-seed scores with rpb (also overlaps staging)
  float s[25];
#pragma unroll
  for (int x = 0; x < 5; ++x)
#pragma unroll
    for (int y = 0; y < 5; ++y)
      s[x * 5 + y] = rpb[head * 81 + (dbh + x) * 9 + (dbw + y)];

  __syncthreads();                 // K staged

  // ---- QK ----
#pragma unroll
  for (int x = 0; x < 5; ++x) {
#pragma unroll
    for (int y = 0; y < 5; ++y) {
      const int r = (oi + x) * 20 + (oj + y);
      float a = 0.0f;
#pragma unroll
      for (int t = 0; t < 6; ++t) {
        bf16x8 kv = *(const bf16x8*)&sm[(r * 7 + t) * 8];
#pragma unroll
        for (int u = 0; u < 8; ++u) a += qv[t * 8 + u] * (float)kv[u];
      }
      s[x * 5 + y] += a;
    }
  }
  __syncthreads();                 // all waves done reading K

  // ---- stage V halo (same slots) ----
#pragma unroll
  for (int it = 0; it < 11; ++it) {
    int ci = tid + it * 256;
    int r = ci / 7;
    int c = ci % 7;
    if (ci < 2800 && c < 6) {
      int hr = r / 20, wr = r % 20;
      const __hip_bfloat16* src =
          qkv + qbase + 192 + (size_t)((hs + hr) * 32 + (ws + wr)) * 576 + c * 8;
      __builtin_amdgcn_global_load_lds((gv_t*)src, (lv_t*)&sm[ci * 8], 16, 0, 0);
    }
  }

  // softmax (overlaps V staging)
  float mx = s[0];
#pragma unroll
  for (int n = 1; n < 25; ++n) mx = fmaxf(mx, s[n]);
  float sum = 0.0f;
#pragma unroll
  for (int n = 0; n < 25; ++n) {
    s[n] = __expf(s[n] - mx);
    sum += s[n];
  }
  const float inv = 1.0f / sum;

  __syncthreads();                 // V staged

  // ---- PV (t-outer, pv[8] live) ----
  bf16x8* op = (bf16x8*)(o + (size_t)pix * 192 + head * 48);
#pragma unroll
  for (int t = 0; t < 6; ++t) {
    float pv[8] = {};
#pragma unroll
    for (int x = 0; x < 5; ++x) {
#pragma unroll
      for (int y = 0; y < 5; ++y) {
        const int r = (oi + x) * 20 + (oj + y);
        const bf16x8 vv = *(const bf16x8*)&sm[(r * 7 + t) * 8];
        const float w = s[x * 5 + y];
#pragma unroll
        for (int u = 0; u < 8; ++u) pv[u] += w * (float)vv[u];
      }
    }
    bf16x8 ov;
#pragma unroll
    for (int u = 0; u < 8; ++u) ov[u] = (__bf16)(pv[u] * inv);
    op[t] = ov;
  }
}

extern "C" void kernel_launch(void* const* d_in, const int* in_sizes, int n_in,
                              void* d_out, int out_size, void* d_ws, size_t ws_size,
                              hipStream_t stream) {
  const float* x       = (const float*)d_in[0];
  const float* fc1_w   = (const float*)d_in[1];
  const float* fc1_b   = (const float*)d_in[2];
  const float* convA_w = (const float*)d_in[3];
  const float* convA_b = (const float*)d_in[4];
  const float* convB_w = (const float*)d_in[5];
  const float* convB_b = (const float*)d_in[6];
  const float* ln_g    = (const float*)d_in[7];
  const float* ln_b    = (const float*)d_in[8];
  const float* qkv_w   = (const float*)d_in[9];
  const float* qkv_b   = (const float*)d_in[10];
  const float* rpb     = (const float*)d_in[11];
  const float* proj_w  = (const float*)d_in[12];
  const float* proj_b  = (const float*)d_in[13];
  const float* fc2_w   = (const float*)d_in[14];
  const float* fc2_b   = (const float*)d_in[15];
  float* out = (float*)d_out;

  const int M = 65536;
  char* W0 = (char*)d_ws;
  __hip_bfloat16* x_bf  = (__hip_bfloat16*)W0;                 // 50,331,648 elems
  __hip_bfloat16* wfc1  = (__hip_bfloat16*)(W0 + 100663296);
  __hip_bfloat16* wcvA  = wfc1 + 147456;
  __hip_bfloat16* wcvB  = wcvA + 12288;
  __hip_bfloat16* wqkv  = wcvB + 12288;
  __hip_bfloat16* wproj = wqkv + 110592;
  __hip_bfloat16* wfc2  = wproj + 36864;
  __hip_bfloat16* reg1  = wfc2 + 147456;                       // 37,748,736 elems
  __hip_bfloat16* xs0   = reg1;
  __hip_bfloat16* bconv = reg1 + 12582912;
  __hip_bfloat16* abuf  = reg1 + 25165824;
  __hip_bfloat16* qkvb  = reg1;
  __hip_bfloat16* ybuf  = reg1;
  __hip_bfloat16* xs_sp = reg1 + 37748736;                     // 12,582,912
  __hip_bfloat16* ln_sp = xs_sp + 12582912;                    // 12,582,912
  __hip_bfloat16* obuf  = ln_sp;                               // reuse after qkv GEMM

  auto cvt = [&](const float* in, __hip_bfloat16* outp, int n) {
    int n4 = n / 4;
    cvt_kernel<<<(n4 + 255) / 256, 256, 0, stream>>>(in, outp, n4);
  };
  cvt(x, x_bf, 50331648);
  cvt(fc1_w, wfc1, 147456);
  cvt(convA_w, wcvA, 12288);
  cvt(convB_w, wcvB, 12288);
  cvt(qkv_w, wqkv, 110592);
  cvt(proj_w, wproj, 36864);
  cvt(fc2_w, wfc2, 147456);

  // 1. fc1
  mfma_gemm_kernel<0><<<dim3(3, 512), 256, 0, stream>>>(
      x_bf, wfc1, fc1_b, nullptr, nullptr, xs0, M, 192, 768);
  // 2. convA
  mfma_gemm_kernel<0><<<dim3(1, 512), 256, 0, stream>>>(
      xs0, wcvA, convA_b, nullptr, nullptr, abuf, M, 64, 192);
  // 3. convB
  mfma_gemm_kernel<0><<<dim3(3, 512), 256, 0, stream>>>(
      abuf, wcvB, convB_b, nullptr, nullptr, bconv, M, 192, 64);
  // 4. gelu + residual + transpose + LN
  fuse_gelu_ln_kernel<<<16384, 256, 0, stream>>>(bconv, xs0, ln_g, ln_b, xs_sp, ln_sp);
  // 5. qkv
  mfma_gemm_kernel<0><<<dim3(9, 512), 256, 0, stream>>>(
      ln_sp, wqkv, qkv_b, nullptr, nullptr, qkvb, M, 576, 192);
  // 6. natten (per-(tile,head) LDS halo, 1024 blocks)
  natten_kernel<<<1024, 256, 0, stream>>>(qkvb, rpb, obuf);
  // 7. proj + residual(xs_sp)
  mfma_gemm_kernel<1><<<dim3(3, 512), 256, 0, stream>>>(
      obuf, wproj, proj_b, xs_sp, nullptr, ybuf, M, 192, 192);
  // 8. fc2 + residual(x) + permuted scatter (swapped-operand, coalesced)
  mfma_gemm_kernel<2><<<dim3(12, 512), 256, 0, stream>>>(
      ybuf, wfc2, fc2_b, nullptr, x, (void*)out, M, 768, 192);
}

// Round 7
// 377.788 us; speedup vs baseline: 1.5501x; 1.2001x over previous
//
#include <hip/hip_runtime.h>
#include <hip/hip_bf16.h>
#include <math.h>

// L=1024, BT=64, D=768, HID=192, NH=4, hd=48, K=5, Hh=Ww=32, T=16, M=65536
//
// bf16 pipeline:
//  cvt: x -> x_bf, weights -> bf16
//  1. xs0   = x_bf @ fc1_w.T + b          (M x 192) bf16, rows m = l*64+b
//  2. a     = xs0 @ convA_w.T + b         (M x 64)  bf16
//  3. bconv = a @ convB_w.T + b           (M x 192) bf16
//  4. fuse: g = gelu(bconv+xs0); xs_sp[spatial]=g; ln_sp=LN(g)   bf16
//  5. qkv   = ln_sp @ qkv_w.T + b         (M x 576) bf16 spatial
//  6. natten -> o                         (M x 192) bf16 (all-LDS, s[25] only)
//  7. y     = o @ proj_w.T + b + xs_sp    (M x 192) bf16 spatial
//  8. out   = scatter(y @ fc2_w.T + b + x)  fp32 permuted, SWAPPED mfma.

typedef __attribute__((ext_vector_type(4))) float f32x4;
typedef __attribute__((ext_vector_type(8))) __bf16 bf16x8;
typedef const __attribute__((address_space(1))) void gv_t;
typedef __attribute__((address_space(3))) void lv_t;

#define GBM 128
#define GBN 64
#define GBK 64

// ---------------- MFMA GEMM: C = A @ W^T + bias (+epilogue) ----------------
template <int MODE>
__global__ __launch_bounds__(256) void mfma_gemm_kernel(
    const __hip_bfloat16* __restrict__ A, const __hip_bfloat16* __restrict__ W,
    const float* __restrict__ bias, const __hip_bfloat16* __restrict__ res,
    const float* __restrict__ xin, void* __restrict__ Cout,
    int M, int N, int K) {
  __shared__ __hip_bfloat16 Asm[2][GBM * GBK];
  __shared__ __hip_bfloat16 Bsm[2][GBN * GBK];

  const int tid = threadIdx.x;
  const int lane = tid & 63;
  const int wave = tid >> 6;

  // chunked XCD swizzle (all grids have nwg % 8 == 0)
  const int gx = gridDim.x;
  const int nwg = gx * gridDim.y;
  int id = blockIdx.y * gx + blockIdx.x;
  id = (id & 7) * (nwg >> 3) + (id >> 3);
  const int bm0 = (id / gx) * GBM;
  const int bn0 = (id % gx) * GBN;

  const int wm0 = (wave >> 1) * 64;
  const int wn0 = (wave & 1) * 32;

  const int l15 = lane & 15;
  const int l7 = lane & 7;
  const int lg = lane >> 4;

  f32x4 acc[4][2] = {};

  int aro[4], bro[2], ksw[2];
#pragma unroll
  for (int mi = 0; mi < 4; ++mi) aro[mi] = (wm0 + mi * 16 + l15) * (GBK * 2);
#pragma unroll
  for (int nj = 0; nj < 2; ++nj) bro[nj] = (wn0 + nj * 16 + l15) * (GBK * 2);
#pragma unroll
  for (int kk = 0; kk < 2; ++kk) ksw[kk] = ((lg * 16 + kk * 64) ^ (l7 << 4));

  const int nk = K / GBK;

  auto stage = [&](int buf, int k0) {
#pragma unroll
    for (int q = 0; q < 4; ++q) {
      int ci = tid + q * 256;            // A chunks (16B each)
      int r = ci >> 3;
      int sc = (ci & 7) ^ (r & 7);
      const __hip_bfloat16* src = A + (size_t)(bm0 + r) * K + (k0 + sc * 8);
      __builtin_amdgcn_global_load_lds((gv_t*)src, (lv_t*)&Asm[buf][ci * 8], 16, 0, 0);
    }
#pragma unroll
    for (int q = 0; q < 2; ++q) {
      int ci = tid + q * 256;            // B chunks
      int r = ci >> 3;
      int sc = (ci & 7) ^ (r & 7);
      const __hip_bfloat16* src = W + (size_t)(bn0 + r) * K + (k0 + sc * 8);
      __builtin_amdgcn_global_load_lds((gv_t*)src, (lv_t*)&Bsm[buf][ci * 8], 16, 0, 0);
    }
  };

  stage(0, 0);
  for (int kt = 0; kt < nk; ++kt) {
    const int cur = kt & 1;
    __syncthreads();
    if (kt + 1 < nk) stage(cur ^ 1, (kt + 1) * GBK);
    const char* Ab = (const char*)&Asm[cur][0];
    const char* Bb = (const char*)&Bsm[cur][0];
#pragma unroll
    for (int kk = 0; kk < 2; ++kk) {
      bf16x8 af[4], bfr[2];
#pragma unroll
      for (int mi = 0; mi < 4; ++mi)
        af[mi] = *(const bf16x8*)(Ab + aro[mi] + ksw[kk]);
#pragma unroll
      for (int nj = 0; nj < 2; ++nj)
        bfr[nj] = *(const bf16x8*)(Bb + bro[nj] + ksw[kk]);
#pragma unroll
      for (int mi = 0; mi < 4; ++mi)
#pragma unroll
        for (int nj = 0; nj < 2; ++nj) {
          if constexpr (MODE == 2)
            acc[mi][nj] = __builtin_amdgcn_mfma_f32_16x16x32_bf16(
                bfr[nj], af[mi], acc[mi][nj], 0, 0, 0);   // D[row=n][col=m]
          else
            acc[mi][nj] = __builtin_amdgcn_mfma_f32_16x16x32_bf16(
                af[mi], bfr[nj], acc[mi][nj], 0, 0, 0);   // D[row=m][col=n]
        }
    }
  }

  if constexpr (MODE == 2) {
    float* Cf = (float*)Cout;
#pragma unroll
    for (int nj = 0; nj < 2; ++nj) {
      const int n0 = bn0 + wn0 + nj * 16 + lg * 4;
      const f32x4 bi4 = *(const f32x4*)(bias + n0);
#pragma unroll
      for (int mi = 0; mi < 4; ++mi) {
        const int m = bm0 + wm0 + mi * 16 + l15;   // col = lane&15 -> m
        const int b = m >> 10;
        const int ll = m & 1023;
        const f32x4 xv = *(const f32x4*)(xin + (size_t)((ll << 6) | b) * 768 + n0);
        const size_t ob = (((size_t)(b >> 4) * 768 + n0) * 16 + (b & 15)) * 1024 + ll;
#pragma unroll
        for (int r = 0; r < 4; ++r) {
          Cf[ob + (size_t)r * 16384] = acc[mi][nj][r] + bi4[r] + xv[r];
        }
      }
    }
  } else {
    __hip_bfloat16* Cb = (__hip_bfloat16*)Cout;
#pragma unroll
    for (int nj = 0; nj < 2; ++nj) {
      const int n = bn0 + wn0 + nj * 16 + l15;
      const float bi = bias[n];
#pragma unroll
      for (int mi = 0; mi < 4; ++mi) {
        const int mb = bm0 + wm0 + mi * 16 + lg * 4;
        f32x4 v = acc[mi][nj];
#pragma unroll
        for (int r = 0; r < 4; ++r) {
          const int m = mb + r;
          float val = v[r] + bi;
          if constexpr (MODE == 1) val += __bfloat162float(res[(size_t)m * N + n]);
          Cb[(size_t)m * N + n] = __float2bfloat16(val);
        }
      }
    }
  }
}

// ---------------- fp32 -> bf16 convert (vectorized) ----------------
__global__ __launch_bounds__(256) void cvt_kernel(
    const float* __restrict__ in, __hip_bfloat16* __restrict__ out, int n4) {
  int i = blockIdx.x * 256 + threadIdx.x;
  if (i >= n4) return;
  float4 v = ((const float4*)in)[i];
  union { unsigned short u[4]; uint2 d; } o;
  __hip_bfloat16 b0 = __float2bfloat16(v.x);
  __hip_bfloat16 b1 = __float2bfloat16(v.y);
  __hip_bfloat16 b2 = __float2bfloat16(v.z);
  __hip_bfloat16 b3 = __float2bfloat16(v.w);
  o.u[0] = *(unsigned short*)&b0; o.u[1] = *(unsigned short*)&b1;
  o.u[2] = *(unsigned short*)&b2; o.u[3] = *(unsigned short*)&b3;
  ((uint2*)out)[i] = o.d;
}

// ---------------- GeLU + residual + transpose + LayerNorm ----------------
__global__ __launch_bounds__(256) void fuse_gelu_ln_kernel(
    const __hip_bfloat16* __restrict__ bconv, const __hip_bfloat16* __restrict__ xs0,
    const float* __restrict__ ln_g, const float* __restrict__ ln_b,
    __hip_bfloat16* __restrict__ xs_sp, __hip_bfloat16* __restrict__ ln_sp) {
  const int r = blockIdx.x * 4 + (threadIdx.x >> 6);  // m = l*64 + b
  const int tid = threadIdx.x & 63;
  const int l = r >> 6;
  const int b = r & 63;
  const size_t src = (size_t)r * 192;
  const size_t dst = (size_t)((b << 10) | l) * 192;

  float g[3];
  float s1 = 0.0f, s2 = 0.0f;
#pragma unroll
  for (int q = 0; q < 3; ++q) {
    int c = tid + q * 64;
    float v = __bfloat162float(bconv[src + c]) + __bfloat162float(xs0[src + c]);
    float ge = 0.5f * v * (1.0f + erff(v * 0.70710678118654752f));
    g[q] = ge;
    s1 += ge;
    s2 += ge * ge;
  }
#pragma unroll
  for (int off = 32; off; off >>= 1) {
    s1 += __shfl_xor(s1, off);
    s2 += __shfl_xor(s2, off);
  }
  float mean = s1 * (1.0f / 192.0f);
  float var = s2 * (1.0f / 192.0f) - mean * mean;
  float rstd = rsqrtf(var + 1e-5f);
#pragma unroll
  for (int q = 0; q < 3; ++q) {
    int c = tid + q * 64;
    xs_sp[dst + c] = __float2bfloat16(g[q]);
    ln_sp[dst + c] = __float2bfloat16((g[q] - mean) * rstd * ln_g[c] + ln_b[c]);
  }
}

// ---------------- Neighborhood attention: all-LDS, minimal reg state -------
// Block = one (16x16 pixel tile, head). 256 threads, 1 pixel/lane.
// LDS: Q tile 256px x 6 granules (24.6KB, own-row reads) + K/V halo 20x20 x
// 48 dims padded to 7 granules/row (45KB; granule (7r+t)%8 coprime-spread ->
// conflict-free b128 reads, linear gload_lds dest).
// QK is t-outer: 1 own-Q chunk (4 regs) + 25 K reads -> s[25] accumulate.
// rpb pre-seeded as rpb*sqrt(48); scale folded into softmax exp argument.
// PV t-outer with pv[8]. Long-lived per-thread state ~ s[25] only.
__global__ __launch_bounds__(256) void natten_kernel(
    const __hip_bfloat16* __restrict__ qkv, const float* __restrict__ rpb,
    __hip_bfloat16* __restrict__ o) {
  __shared__ __hip_bfloat16 kv_s[2816 * 8];   // 45056 B (16 pad slots incl.)
  __shared__ __hip_bfloat16 q_s[1536 * 8];    // 24576 B

  const int tid = threadIdx.x;
  const int bid = blockIdx.x;      // 1024 = 64 img * 2*2 tiles * 4 heads
  const int head = bid & 3;
  const int tj = (bid >> 2) & 1;
  const int ti = (bid >> 3) & 1;
  const int b = bid >> 4;

  const int hs = ti * 12;          // halo start (20 rows cover 16+2+2 clamped)
  const int ws = tj * 12;
  const int i = ti * 16 + (tid >> 4);
  const int j = tj * 16 + (tid & 15);
  const int pix = (b << 10) + (i << 5) + j;
  const int ih0 = min(max(i - 2, 0), 27);
  const int iw0 = min(max(j - 2, 0), 27);
  const int oi = ih0 - hs;         // halo-local
  const int oj = iw0 - ws;
  const int dbh = ih0 - i + 4;
  const int dbw = iw0 - j + 4;
  const size_t kbase = (size_t)(b << 10) * 576 + 192 + head * 48;  // K seg

  // ---- stage Q tile (1536 granules, no guard) ----
#pragma unroll
  for (int it = 0; it < 6; ++it) {
    int ci = tid + it * 256;
    int px = ci / 6, c = ci % 6;
    int pi = ti * 16 + (px >> 4), pj = tj * 16 + (px & 15);
    const __hip_bfloat16* src =
        qkv + (size_t)((b << 10) + (pi << 5) + pj) * 576 + head * 48 + c * 8;
    __builtin_amdgcn_global_load_lds((gv_t*)src, (lv_t*)&q_s[ci * 8], 16, 0, 0);
  }
  // ---- stage K halo (2816 granules incl. 403rd-row/7th-chunk pad: garbage,
  //      never read, src stays inside d_ws) ----
#pragma unroll
  for (int it = 0; it < 11; ++it) {
    int ci = tid + it * 256;
    int r = ci / 7, c = ci % 7;
    int hr = r / 20, wr = r % 20;
    const __hip_bfloat16* src =
        qkv + kbase + (size_t)((hs + hr) * 32 + (ws + wr)) * 576 + c * 8;
    __builtin_amdgcn_global_load_lds((gv_t*)src, (lv_t*)&kv_s[ci * 8], 16, 0, 0);
  }

  // seed scores with rpb * sqrt(48)  (scale applied inside exp later)
  float s[25];
#pragma unroll
  for (int x = 0; x < 5; ++x)
#pragma unroll
    for (int y = 0; y < 5; ++y)
      s[x * 5 + y] = rpb[head * 81 + (dbh + x) * 9 + (dbw + y)] * 6.9282032302755092f;

  __syncthreads();                 // Q + K staged

  // ---- QK, t-outer ----
  const char* qb = (const char*)q_s + tid * 96;
  const char* kvb = (const char*)kv_s + (oi * 20 + oj) * 112;
#pragma unroll
  for (int t = 0; t < 6; ++t) {
    const bf16x8 qv = *(const bf16x8*)(qb + t * 16);
#pragma unroll
    for (int x = 0; x < 5; ++x) {
#pragma unroll
      for (int y = 0; y < 5; ++y) {
        const bf16x8 kv = *(const bf16x8*)(kvb + (x * 20 + y) * 112 + t * 16);
        float a = 0.0f;
#pragma unroll
        for (int u = 0; u < 8; ++u) a += (float)qv[u] * (float)kv[u];
        s[x * 5 + y] += a;
      }
    }
  }
  __syncthreads();                 // all waves done reading K

  // ---- stage V halo (same slots) ----
#pragma unroll
  for (int it = 0; it < 11; ++it) {
    int ci = tid + it * 256;
    int r = ci / 7, c = ci % 7;
    int hr = r / 20, wr = r % 20;
    const __hip_bfloat16* src =
        qkv + kbase + 192 + (size_t)((hs + hr) * 32 + (ws + wr)) * 576 + c * 8;
    __builtin_amdgcn_global_load_lds((gv_t*)src, (lv_t*)&kv_s[ci * 8], 16, 0, 0);
  }

  // softmax (overlaps V staging); scale folded: e = exp((s-mx)*scale)
  float mx = s[0];
#pragma unroll
  for (int n = 1; n < 25; ++n) mx = fmaxf(mx, s[n]);
  float sum = 0.0f;
#pragma unroll
  for (int n = 0; n < 25; ++n) {
    s[n] = __expf((s[n] - mx) * 0.14433756729740643f);
    sum += s[n];
  }
  const float inv = 1.0f / sum;

  __syncthreads();                 // V staged

  // ---- PV (t-outer, pv[8] live) ----
  bf16x8* op = (bf16x8*)(o + (size_t)pix * 192 + head * 48);
#pragma unroll
  for (int t = 0; t < 6; ++t) {
    float pv[8] = {};
#pragma unroll
    for (int x = 0; x < 5; ++x) {
#pragma unroll
      for (int y = 0; y < 5; ++y) {
        const bf16x8 vv = *(const bf16x8*)(kvb + (x * 20 + y) * 112 + t * 16);
        const float w = s[x * 5 + y];
#pragma unroll
        for (int u = 0; u < 8; ++u) pv[u] += w * (float)vv[u];
      }
    }
    bf16x8 ov;
#pragma unroll
    for (int u = 0; u < 8; ++u) ov[u] = (__bf16)(pv[u] * inv);
    op[t] = ov;
  }
}

extern "C" void kernel_launch(void* const* d_in, const int* in_sizes, int n_in,
                              void* d_out, int out_size, void* d_ws, size_t ws_size,
                              hipStream_t stream) {
  const float* x       = (const float*)d_in[0];
  const float* fc1_w   = (const float*)d_in[1];
  const float* fc1_b   = (const float*)d_in[2];
  const float* convA_w = (const float*)d_in[3];
  const float* convA_b = (const float*)d_in[4];
  const float* convB_w = (const float*)d_in[5];
  const float* convB_b = (const float*)d_in[6];
  const float* ln_g    = (const float*)d_in[7];
  const float* ln_b    = (const float*)d_in[8];
  const float* qkv_w   = (const float*)d_in[9];
  const float* qkv_b   = (const float*)d_in[10];
  const float* rpb     = (const float*)d_in[11];
  const float* proj_w  = (const float*)d_in[12];
  const float* proj_b  = (const float*)d_in[13];
  const float* fc2_w   = (const float*)d_in[14];
  const float* fc2_b   = (const float*)d_in[15];
  float* out = (float*)d_out;

  const int M = 65536;
  char* W0 = (char*)d_ws;
  __hip_bfloat16* x_bf  = (__hip_bfloat16*)W0;                 // 50,331,648 elems
  __hip_bfloat16* wfc1  = (__hip_bfloat16*)(W0 + 100663296);
  __hip_bfloat16* wcvA  = wfc1 + 147456;
  __hip_bfloat16* wcvB  = wcvA + 12288;
  __hip_bfloat16* wqkv  = wcvB + 12288;
  __hip_bfloat16* wproj = wqkv + 110592;
  __hip_bfloat16* wfc2  = wproj + 36864;
  __hip_bfloat16* reg1  = wfc2 + 147456;                       // 37,748,736 elems
  __hip_bfloat16* xs0   = reg1;
  __hip_bfloat16* bconv = reg1 + 12582912;
  __hip_bfloat16* abuf  = reg1 + 25165824;
  __hip_bfloat16* qkvb  = reg1;
  __hip_bfloat16* ybuf  = reg1;
  __hip_bfloat16* xs_sp = reg1 + 37748736;                     // 12,582,912
  __hip_bfloat16* ln_sp = xs_sp + 12582912;                    // 12,582,912
  __hip_bfloat16* obuf  = ln_sp;                               // reuse after qkv GEMM

  auto cvt = [&](const float* in, __hip_bfloat16* outp, int n) {
    int n4 = n / 4;
    cvt_kernel<<<(n4 + 255) / 256, 256, 0, stream>>>(in, outp, n4);
  };
  cvt(x, x_bf, 50331648);
  cvt(fc1_w, wfc1, 147456);
  cvt(convA_w, wcvA, 12288);
  cvt(convB_w, wcvB, 12288);
  cvt(qkv_w, wqkv, 110592);
  cvt(proj_w, wproj, 36864);
  cvt(fc2_w, wfc2, 147456);

  // 1. fc1
  mfma_gemm_kernel<0><<<dim3(3, 512), 256, 0, stream>>>(
      x_bf, wfc1, fc1_b, nullptr, nullptr, xs0, M, 192, 768);
  // 2. convA
  mfma_gemm_kernel<0><<<dim3(1, 512), 256, 0, stream>>>(
      xs0, wcvA, convA_b, nullptr, nullptr, abuf, M, 64, 192);
  // 3. convB
  mfma_gemm_kernel<0><<<dim3(3, 512), 256, 0, stream>>>(
      abuf, wcvB, convB_b, nullptr, nullptr, bconv, M, 192, 64);
  // 4. gelu + residual + transpose + LN
  fuse_gelu_ln_kernel<<<16384, 256, 0, stream>>>(bconv, xs0, ln_g, ln_b, xs_sp, ln_sp);
  // 5. qkv
  mfma_gemm_kernel<0><<<dim3(9, 512), 256, 0, stream>>>(
      ln_sp, wqkv, qkv_b, nullptr, nullptr, qkvb, M, 576, 192);
  // 6. natten (all-LDS, 1024 blocks)
  natten_kernel<<<1024, 256, 0, stream>>>(qkvb, rpb, obuf);
  // 7. proj + residual(xs_sp)
  mfma_gemm_kernel<1><<<dim3(3, 512), 256, 0, stream>>>(
      obuf, wproj, proj_b, xs_sp, nullptr, ybuf, M, 192, 192);
  // 8. fc2 + residual(x) + permuted scatter (swapped-operand, coalesced)
  mfma_gemm_kernel<2><<<dim3(12, 512), 256, 0, stream>>>(
      ybuf, wfc2, fc2_b, nullptr, x, (void*)out, M, 768, 192);
}